// Round 2
// baseline (416.284 us; speedup 1.0000x reference)
//
#include <hip/hip_runtime.h>
#include <hip/hip_bf16.h>
#include <math.h>

#define BB 128
#define PP 8732
#define NN 16
#define CC 81
#define IMG 300.0f
#define K2_BLOCKS 8192

// ---------------------------------------------------------------------------
// Kernel 1: per-image matching + bbox loss partials
// grid = BB blocks, 1024 threads
// ---------------------------------------------------------------------------
__global__ __launch_bounds__(1024) void k1_match(
    const float* __restrict__ pred_boxes,   // [B,P,4]
    const float* __restrict__ tgt_boxes,    // [B,N,4] pixel cxcywh
    const int*   __restrict__ tgt_labels,   // [B,N]
    const float* __restrict__ dboxes,       // [P,4] cxcywh (clipped)
    int*   __restrict__ tlab_out,           // [B,P]
    float* __restrict__ bbox_partial,       // [B]
    int*   __restrict__ pos_count)          // [B]
{
    const int b   = blockIdx.x;
    const int tid = threadIdx.x;

    __shared__ float t_cx[NN], t_cy[NN], t_w[NN], t_h[NN];
    __shared__ float t_x0[NN], t_y0[NN], t_x1[NN], t_y1[NN], t_area[NN];
    __shared__ int   t_lab[NN];
    __shared__ unsigned short obj_s[PP];
    __shared__ unsigned char  chk_s[PP];
    __shared__ float red_v[NN][16];
    __shared__ int   red_i[NN][16];
    __shared__ int   box_idx_s[NN];
    __shared__ float red_f[16];
    __shared__ int   red_c[16];

    if (tid < NN) {
        const float* tb = tgt_boxes + ((size_t)b * NN + tid) * 4;
        float cx = tb[0] / IMG, cy = tb[1] / IMG, w = tb[2] / IMG, h = tb[3] / IMG;
        t_cx[tid] = cx; t_cy[tid] = cy; t_w[tid] = w; t_h[tid] = h;
        float x0 = cx - w * 0.5f, y0 = cy - h * 0.5f;
        float x1 = cx + w * 0.5f, y1 = cy + h * 0.5f;
        t_x0[tid] = x0; t_y0[tid] = y0; t_x1[tid] = x1; t_y1[tid] = y1;
        t_area[tid] = (x1 - x0) * (y1 - y0);
        t_lab[tid] = tgt_labels[(size_t)b * NN + tid];
    }
    __syncthreads();

    // Phase A: per-prior best object; per-object running best prior
    float bestv[NN];
    int   bestp[NN];
#pragma unroll
    for (int n = 0; n < NN; ++n) { bestv[n] = -1e30f; bestp[n] = 0x7fffffff; }

    for (int p = tid; p < PP; p += 1024) {
        float4 d = *reinterpret_cast<const float4*>(dboxes + (size_t)p * 4);
        float dx0 = d.x - d.z * 0.5f, dy0 = d.y - d.w * 0.5f;
        float dx1 = d.x + d.z * 0.5f, dy1 = d.y + d.w * 0.5f;
        float dar = (dx1 - dx0) * (dy1 - dy0);
        float bov = -1.0f; int bidx = 0;
#pragma unroll
        for (int n = 0; n < NN; ++n) {
            float lx = fmaxf(t_x0[n], dx0);
            float ly = fmaxf(t_y0[n], dy0);
            float rx = fminf(t_x1[n], dx1);
            float ry = fminf(t_y1[n], dy1);
            float iw = fmaxf(rx - lx, 0.0f);
            float ih = fmaxf(ry - ly, 0.0f);
            float inter = iw * ih;
            float iou = inter / (t_area[n] + dar - inter);
            if (iou > bov) { bov = iou; bidx = n; }               // first-max over n
            if (iou > bestv[n]) { bestv[n] = iou; bestp[n] = p; } // first-max over p
        }
        obj_s[p] = (unsigned short)bidx;
        chk_s[p] = (bov > 0.5f) ? 1 : 0;
    }

    // Phase B: block-wide argmax per object (tie -> smaller p)
#pragma unroll
    for (int n = 0; n < NN; ++n) {
        float v = bestv[n]; int ip = bestp[n];
        for (int off = 32; off; off >>= 1) {
            float v2 = __shfl_xor(v, off);
            int   p2 = __shfl_xor(ip, off);
            if (v2 > v || (v2 == v && p2 < ip)) { v = v2; ip = p2; }
        }
        if ((tid & 63) == 0) { red_v[n][tid >> 6] = v; red_i[n][tid >> 6] = ip; }
    }
    __syncthreads();
    if (tid < NN) {
        float v = red_v[tid][0]; int ip = red_i[tid][0];
        for (int w = 1; w < 16; ++w) {
            float v2 = red_v[tid][w]; int p2 = red_i[tid][w];
            if (v2 > v || (v2 == v && p2 < ip)) { v = v2; ip = p2; }
        }
        box_idx_s[tid] = ip;
    }
    __syncthreads();
    // Phase C: scatter (numpy last-wins, n ascending)
    if (tid == 0) {
        for (int n = 0; n < NN; ++n) obj_s[box_idx_s[n]] = (unsigned short)n;
    }
    __syncthreads();

    // Phase D: labels, encode, smoothL1 over positives
    float bacc = 0.0f;
    int   pcnt = 0;
    for (int p = tid; p < PP; p += 1024) {
        int lab = 0;
        if (chk_s[p]) {
            int n = obj_s[p];
            lab = t_lab[n];
            if (lab != 0) {
                ++pcnt;
                float4 d = *reinterpret_cast<const float4*>(dboxes + (size_t)p * 4);
                float gx = (t_cx[n] - d.x) / (d.z / 10.0f);
                float gy = (t_cy[n] - d.y) / (d.w / 10.0f);
                float gw = logf(t_w[n] / d.z) * 5.0f;
                float gh = logf(t_h[n] / d.w) * 5.0f;
                float4 pv = *reinterpret_cast<const float4*>(pred_boxes + ((size_t)b * PP + p) * 4);
                float dfs[4] = { pv.x - gx, pv.y - gy, pv.z - gw, pv.w - gh };
#pragma unroll
                for (int j = 0; j < 4; ++j) {
                    float ad = fabsf(dfs[j]);
                    bacc += (ad < 1.0f) ? 0.5f * ad * ad : ad - 0.5f;
                }
            }
        }
        tlab_out[(size_t)b * PP + p] = lab;
    }
    for (int off = 32; off; off >>= 1) {
        bacc += __shfl_xor(bacc, off);
        pcnt += __shfl_xor(pcnt, off);
    }
    if ((tid & 63) == 0) { red_f[tid >> 6] = bacc; red_c[tid >> 6] = pcnt; }
    __syncthreads();
    if (tid == 0) {
        float s = 0.0f; int c = 0;
        for (int w = 0; w < 16; ++w) { s += red_f[w]; c += red_c[w]; }
        bbox_partial[b] = s;
        pos_count[b]    = c;
    }
}

// ---------------------------------------------------------------------------
// Kernel 2: per-row cross entropy, 32 lanes per row (2 rows per wave).
// Loads are two fully-used 128B contiguous segments per wave instruction.
// ROWS % 8 == 0, so every block-iteration's 8 rows are all valid.
// grid = K2_BLOCKS x 256
// ---------------------------------------------------------------------------
__global__ __launch_bounds__(256) void k2_cls(
    const float* __restrict__ scores,  // [B*P, C]
    const int*   __restrict__ tlab,    // [B*P]
    float* __restrict__ neg,           // [B*P]
    float* __restrict__ clspos_partial)// [K2_BLOCKS]
{
    const long long ROWS = (long long)BB * PP;   // 1,117,696 = 8 * 139,712
    const int tid  = threadIdx.x;
    const int l32  = tid & 31;
    const int half = (tid >> 5) & 1;
    const int wv   = tid >> 6;            // wave index in block, 0..3

    float acc = 0.0f;
    for (long long r0 = (long long)blockIdx.x * 8; r0 < ROWS;
         r0 += (long long)gridDim.x * 8) {
        long long r = r0 + wv * 2 + half;
        const float* row = scores + (size_t)r * CC;
        float x0 = row[l32];
        float x1 = row[l32 + 32];
        float x2 = (l32 + 64 < CC) ? row[l32 + 64] : -1e30f;
        float m = fmaxf(fmaxf(x0, x1), x2);
#pragma unroll
        for (int off = 16; off; off >>= 1) m = fmaxf(m, __shfl_xor(m, off));
        float s = __expf(x0 - m) + __expf(x1 - m) + __expf(x2 - m);
#pragma unroll
        for (int off = 16; off; off >>= 1) s += __shfl_xor(s, off);
        if (l32 == 0) {
            int   lab = tlab[r];
            float cls = m + __logf(s) - row[lab];
            if (lab != 0) { acc += cls; neg[r] = 0.0f; }
            else          { neg[r] = cls; }
        }
    }
    // block reduce acc (fixed topology)
    for (int off = 32; off; off >>= 1) acc += __shfl_xor(acc, off);
    __shared__ float wsum[4];
    if ((tid & 63) == 0) wsum[tid >> 6] = acc;
    __syncthreads();
    if (tid == 0)
        clspos_partial[blockIdx.x] = wsum[0] + wsum[1] + wsum[2] + wsum[3];
}

// ---------------------------------------------------------------------------
// Kernel 3: per-image sum of top-k negatives via exact radix select.
// Histogram uses leader/ballot match-any aggregation: one LDS atomic per
// distinct bin per wave-iteration (round 0 concentrates in ~2-4 exponent
// bins -> this avoids 64-way same-address serialization).
// grid = BB x 256
// ---------------------------------------------------------------------------
__global__ __launch_bounds__(256) void k3_topk(
    const float* __restrict__ neg,
    const int*   __restrict__ pos_count,
    float* __restrict__ hard_partial)
{
    const int b    = blockIdx.x;
    const int tid  = threadIdx.x;
    const int lane = tid & 63;

    __shared__ unsigned int vals[PP];
    __shared__ int hist[256];
    __shared__ int scn[256];
    __shared__ unsigned int s_prefix;
    __shared__ int s_kk;
    __shared__ float wsum[4];

    // coalesced uint4 load into LDS (PP % 4 == 0)
    const uint4* src = reinterpret_cast<const uint4*>(neg + (size_t)b * PP);
    uint4* dst = reinterpret_cast<uint4*>(vals);
    for (int i = tid; i < PP / 4; i += 256) dst[i] = src[i];

    int k = pos_count[b] * 3;
    if (k > PP) k = PP;
    if (k <= 0) {
        if (tid == 0) hard_partial[b] = 0.0f;
        return;
    }
    if (tid == 0) { s_prefix = 0u; s_kk = k; }
    __syncthreads();

    unsigned int prefmask = 0u;
    for (int round = 0; round < 4; ++round) {
        const int shift = 24 - 8 * round;
        hist[tid] = 0;
        __syncthreads();                       // publishes s_prefix/s_kk + hist zero
        unsigned int pref = s_prefix;
        for (int i = tid; i < PP; i += 256) {
            unsigned int v = vals[i];
            bool p  = ((v & prefmask) == pref);
            int bin = (int)((v >> shift) & 0xFFu);
            unsigned long long act = __ballot(p);
            while (act) {
                int leader = __ffsll((long long)act) - 1;
                int lbin   = __shfl(bin, leader);
                unsigned long long match = __ballot(p && (bin == lbin));
                if (lane == leader) atomicAdd(&hist[lbin], (int)__popcll(match));
                act &= ~match;
            }
        }
        __syncthreads();
        scn[tid] = hist[tid];
        __syncthreads();
        for (int off = 1; off < 256; off <<= 1) {
            int add = (tid + off < 256) ? scn[tid + off] : 0;
            __syncthreads();
            scn[tid] += add;                   // suffix (descending) inclusive scan
            __syncthreads();
        }
        int sg = scn[tid] - hist[tid];         // count strictly greater than bin tid
        int kk = s_kk;
        __syncthreads();                       // all kk reads done before write
        if (sg < kk && sg + hist[tid] >= kk) { // exactly one bin satisfies
            s_prefix = pref | ((unsigned int)tid << shift);
            s_kk     = kk - sg;
        }
        __syncthreads();
        prefmask |= (0xFFu << shift);
    }

    unsigned int t = s_prefix;   // exact bits of k-th largest value
    int kk = s_kk;               // # of t-valued entries inside top-k
    float tf = __uint_as_float(t);

    float acc = 0.0f;
    for (int i = tid; i < PP; i += 256) {
        unsigned int v = vals[i];
        if (v > t) acc += __uint_as_float(v);
    }
    for (int off = 32; off; off >>= 1) acc += __shfl_xor(acc, off);
    if ((tid & 63) == 0) wsum[tid >> 6] = acc;
    __syncthreads();
    if (tid == 0)
        hard_partial[b] = wsum[0] + wsum[1] + wsum[2] + wsum[3] + (float)kk * tf;
}

// ---------------------------------------------------------------------------
// Kernel 4: combine
// ---------------------------------------------------------------------------
__global__ __launch_bounds__(256) void k4_final(
    const float* __restrict__ clspos_partial,
    const float* __restrict__ bbox_partial,
    const float* __restrict__ hard_partial,
    const int*   __restrict__ pos_count,
    float* __restrict__ out)
{
    const int tid = threadIdx.x;
    float cacc = 0.0f, bacc = 0.0f, hacc = 0.0f;
    int   pacc = 0;
    for (int i = tid; i < K2_BLOCKS; i += 256) cacc += clspos_partial[i];
    if (tid < BB) {
        bacc = bbox_partial[tid];
        hacc = hard_partial[tid];
        pacc = pos_count[tid];
    }
    __shared__ float sc[256], sb[256], sh[256];
    __shared__ int   sp[256];
    sc[tid] = cacc; sb[tid] = bacc; sh[tid] = hacc; sp[tid] = pacc;
    __syncthreads();
    for (int off = 128; off; off >>= 1) {
        if (tid < off) {
            sc[tid] += sc[tid + off];
            sb[tid] += sb[tid + off];
            sh[tid] += sh[tid + off];
            sp[tid] += sp[tid + off];
        }
        __syncthreads();
    }
    if (tid == 0) {
        float npos = fmaxf((float)sp[0], 1.0f);
        out[0] = (sc[0] + sh[0]) / npos + sb[0] / (npos * 4.0f);
    }
}

// ---------------------------------------------------------------------------
extern "C" void kernel_launch(void* const* d_in, const int* in_sizes, int n_in,
                              void* d_out, int out_size, void* d_ws, size_t ws_size,
                              hipStream_t stream) {
    const float* pred_boxes  = (const float*)d_in[0];
    const float* pred_scores = (const float*)d_in[1];
    const float* tgt_boxes   = (const float*)d_in[2];
    const int*   tgt_labels  = (const int*)d_in[3];
    const float* dboxes      = (const float*)d_in[4];
    float* out = (float*)d_out;

    char* ws = (char*)d_ws;
    int*   tlab           = (int*)ws;   ws += (size_t)BB * PP * sizeof(int);
    float* neg            = (float*)ws; ws += (size_t)BB * PP * sizeof(float);
    int*   pos_count      = (int*)ws;   ws += BB * sizeof(int);
    float* bbox_partial   = (float*)ws; ws += BB * sizeof(float);
    float* hard_partial   = (float*)ws; ws += BB * sizeof(float);
    float* clspos_partial = (float*)ws; ws += K2_BLOCKS * sizeof(float);

    k1_match<<<BB, 1024, 0, stream>>>(pred_boxes, tgt_boxes, tgt_labels, dboxes,
                                      tlab, bbox_partial, pos_count);
    k2_cls<<<K2_BLOCKS, 256, 0, stream>>>(pred_scores, tlab, neg, clspos_partial);
    k3_topk<<<BB, 256, 0, stream>>>(neg, pos_count, hard_partial);
    k4_final<<<1, 256, 0, stream>>>(clspos_partial, bbox_partial, hard_partial,
                                    pos_count, out);
}

// Round 3
// 170.987 us; speedup vs baseline: 2.4346x; 2.4346x over previous
//
#include <hip/hip_runtime.h>
#include <hip/hip_bf16.h>
#include <math.h>

#define BB 128
#define PP 8732
#define NN 16
#define CC 81
#define IMG 300.0f
#define K2_BLOCKS 4096
#define K1_THREADS 512

// ---------------------------------------------------------------------------
// Kernel 1: per-image matching + bbox loss partials.
// v2: targets held in REGISTERS (not re-read from LDS 128x per prior-iter).
// grid = BB blocks, 512 threads
// ---------------------------------------------------------------------------
__global__ __launch_bounds__(K1_THREADS) void k1_match(
    const float* __restrict__ pred_boxes,   // [B,P,4]
    const float* __restrict__ tgt_boxes,    // [B,N,4] pixel cxcywh
    const int*   __restrict__ tgt_labels,   // [B,N]
    const float* __restrict__ dboxes,       // [P,4] cxcywh (clipped)
    int*   __restrict__ tlab_out,           // [B,P]
    float* __restrict__ bbox_partial,       // [B]
    int*   __restrict__ pos_count)          // [B]
{
    const int b   = blockIdx.x;
    const int tid = threadIdx.x;
    const int NW  = K1_THREADS / 64;

    __shared__ float t_cx[NN], t_cy[NN], t_w[NN], t_h[NN];
    __shared__ float t_x0s[NN], t_y0s[NN], t_x1s[NN], t_y1s[NN], t_areas[NN];
    __shared__ int   t_lab[NN];
    __shared__ unsigned short obj_s[PP];
    __shared__ unsigned char  chk_s[PP];
    __shared__ float red_v[NN][NW];
    __shared__ int   red_i[NN][NW];
    __shared__ int   box_idx_s[NN];
    __shared__ float red_f[NW];
    __shared__ int   red_c[NW];

    if (tid < NN) {
        const float* tb = tgt_boxes + ((size_t)b * NN + tid) * 4;
        float cx = tb[0] / IMG, cy = tb[1] / IMG, w = tb[2] / IMG, h = tb[3] / IMG;
        t_cx[tid] = cx; t_cy[tid] = cy; t_w[tid] = w; t_h[tid] = h;
        float x0 = cx - w * 0.5f, y0 = cy - h * 0.5f;
        float x1 = cx + w * 0.5f, y1 = cy + h * 0.5f;
        t_x0s[tid] = x0; t_y0s[tid] = y0; t_x1s[tid] = x1; t_y1s[tid] = y1;
        t_areas[tid] = (x1 - x0) * (y1 - y0);
        t_lab[tid] = tgt_labels[(size_t)b * NN + tid];
    }
    __syncthreads();

    // Hoist targets to registers (static indexing only -> stays in VGPRs)
    float tx0[NN], ty0[NN], tx1[NN], ty1[NN], tar[NN];
#pragma unroll
    for (int n = 0; n < NN; ++n) {
        tx0[n] = t_x0s[n]; ty0[n] = t_y0s[n];
        tx1[n] = t_x1s[n]; ty1[n] = t_y1s[n];
        tar[n] = t_areas[n];
    }

    // Phase A: per-prior best object; per-object running best prior
    float bestv[NN];
    int   bestp[NN];
#pragma unroll
    for (int n = 0; n < NN; ++n) { bestv[n] = -1e30f; bestp[n] = 0x7fffffff; }

    for (int p = tid; p < PP; p += K1_THREADS) {
        float4 d = *reinterpret_cast<const float4*>(dboxes + (size_t)p * 4);
        float dx0 = d.x - d.z * 0.5f, dy0 = d.y - d.w * 0.5f;
        float dx1 = d.x + d.z * 0.5f, dy1 = d.y + d.w * 0.5f;
        float dar = (dx1 - dx0) * (dy1 - dy0);
        float bov = -1.0f; int bidx = 0;
#pragma unroll
        for (int n = 0; n < NN; ++n) {
            float lx = fmaxf(tx0[n], dx0);
            float ly = fmaxf(ty0[n], dy0);
            float rx = fminf(tx1[n], dx1);
            float ry = fminf(ty1[n], dy1);
            float iw = fmaxf(rx - lx, 0.0f);
            float ih = fmaxf(ry - ly, 0.0f);
            float inter = iw * ih;
            float iou = inter / (tar[n] + dar - inter);
            if (iou > bov) { bov = iou; bidx = n; }               // first-max over n
            if (iou > bestv[n]) { bestv[n] = iou; bestp[n] = p; } // first-max over p
        }
        obj_s[p] = (unsigned short)bidx;
        chk_s[p] = (bov > 0.5f) ? 1 : 0;
    }

    // Phase B: block-wide argmax per object (tie -> smaller p)
#pragma unroll
    for (int n = 0; n < NN; ++n) {
        float v = bestv[n]; int ip = bestp[n];
        for (int off = 32; off; off >>= 1) {
            float v2 = __shfl_xor(v, off);
            int   p2 = __shfl_xor(ip, off);
            if (v2 > v || (v2 == v && p2 < ip)) { v = v2; ip = p2; }
        }
        if ((tid & 63) == 0) { red_v[n][tid >> 6] = v; red_i[n][tid >> 6] = ip; }
    }
    __syncthreads();
    if (tid < NN) {
        float v = red_v[tid][0]; int ip = red_i[tid][0];
        for (int w = 1; w < NW; ++w) {
            float v2 = red_v[tid][w]; int p2 = red_i[tid][w];
            if (v2 > v || (v2 == v && p2 < ip)) { v = v2; ip = p2; }
        }
        box_idx_s[tid] = ip;
    }
    __syncthreads();
    // Phase C: scatter (numpy last-wins, n ascending)
    if (tid == 0) {
        for (int n = 0; n < NN; ++n) obj_s[box_idx_s[n]] = (unsigned short)n;
    }
    __syncthreads();

    // Phase D: labels, encode, smoothL1 over positives
    float bacc = 0.0f;
    int   pcnt = 0;
    for (int p = tid; p < PP; p += K1_THREADS) {
        int lab = 0;
        if (chk_s[p]) {
            int n = obj_s[p];
            lab = t_lab[n];
            if (lab != 0) {
                ++pcnt;
                float4 d = *reinterpret_cast<const float4*>(dboxes + (size_t)p * 4);
                float gx = (t_cx[n] - d.x) / (d.z / 10.0f);
                float gy = (t_cy[n] - d.y) / (d.w / 10.0f);
                float gw = logf(t_w[n] / d.z) * 5.0f;
                float gh = logf(t_h[n] / d.w) * 5.0f;
                float4 pv = *reinterpret_cast<const float4*>(pred_boxes + ((size_t)b * PP + p) * 4);
                float dfs[4] = { pv.x - gx, pv.y - gy, pv.z - gw, pv.w - gh };
#pragma unroll
                for (int j = 0; j < 4; ++j) {
                    float ad = fabsf(dfs[j]);
                    bacc += (ad < 1.0f) ? 0.5f * ad * ad : ad - 0.5f;
                }
            }
        }
        tlab_out[(size_t)b * PP + p] = lab;
    }
    for (int off = 32; off; off >>= 1) {
        bacc += __shfl_xor(bacc, off);
        pcnt += __shfl_xor(pcnt, off);
    }
    if ((tid & 63) == 0) { red_f[tid >> 6] = bacc; red_c[tid >> 6] = pcnt; }
    __syncthreads();
    if (tid == 0) {
        float s = 0.0f; int c = 0;
        for (int w = 0; w < NW; ++w) { s += red_f[w]; c += red_c[w]; }
        bbox_partial[b] = s;
        pos_count[b]    = c;
    }
}

// ---------------------------------------------------------------------------
// Kernel 2: per-row cross entropy (log-softmax over C=81); 16 lanes per row.
// (exact round-1 version -- known-good 204us baseline component)
// grid = K2_BLOCKS x 256
// ---------------------------------------------------------------------------
__global__ __launch_bounds__(256) void k2_cls(
    const float* __restrict__ scores,  // [B*P, C]
    const int*   __restrict__ tlab,    // [B*P]
    float* __restrict__ neg,           // [B*P]
    float* __restrict__ clspos_partial)// [K2_BLOCKS]
{
    const long long ROWS = (long long)BB * PP;
    const int tid    = threadIdx.x;
    const int lane16 = tid & 15;
    const int grp    = tid >> 4;   // 0..15

    float acc = 0.0f;
    for (long long r0 = (long long)blockIdx.x * 16; r0 < ROWS;
         r0 += (long long)gridDim.x * 16) {
        long long r = r0 + grp;
        if (r < ROWS) {
            const float* row = scores + (size_t)r * CC;
            float x[6];
#pragma unroll
            for (int e = 0; e < 6; ++e) {
                int c = lane16 + e * 16;
                x[e] = (c < CC) ? row[c] : -1e30f;
            }
            float m = x[0];
#pragma unroll
            for (int e = 1; e < 6; ++e) m = fmaxf(m, x[e]);
            float s = 0.0f;
#pragma unroll
            for (int e = 0; e < 6; ++e) s += __expf(x[e] - m);
            for (int off = 8; off; off >>= 1) {
                float m2 = __shfl_xor(m, off);
                float s2 = __shfl_xor(s, off);
                float mn = fmaxf(m, m2);
                s = s * __expf(m - mn) + s2 * __expf(m2 - mn);
                m = mn;
            }
            if (lane16 == 0) {
                int   lab = tlab[r];
                float sl  = row[lab];
                float cls = m + __logf(s) - sl;
                if (lab != 0) { acc += cls; neg[r] = 0.0f; }
                else          { neg[r] = cls; }
            }
        }
    }
    for (int off = 32; off; off >>= 1) acc += __shfl_xor(acc, off);
    __shared__ float wsum[4];
    if ((tid & 63) == 0) wsum[tid >> 6] = acc;
    __syncthreads();
    if (tid == 0)
        clspos_partial[blockIdx.x] = wsum[0] + wsum[1] + wsum[2] + wsum[3];
}

// ---------------------------------------------------------------------------
// Kernel 3: per-image sum of top-k negatives via exact radix select.
// (exact round-1 version: plain LDS atomics -- known-good)
// grid = BB x 256
// ---------------------------------------------------------------------------
__global__ __launch_bounds__(256) void k3_topk(
    const float* __restrict__ neg,
    const int*   __restrict__ pos_count,
    float* __restrict__ hard_partial)
{
    const int b   = blockIdx.x;
    const int tid = threadIdx.x;

    __shared__ unsigned int vals[PP];
    __shared__ int hist[256];
    __shared__ int scan[256];
    __shared__ unsigned int s_prefix;
    __shared__ int s_kk;
    __shared__ float wsum[4];

    for (int i = tid; i < PP; i += 256)
        vals[i] = __float_as_uint(neg[(size_t)b * PP + i]);

    int k = pos_count[b] * 3;
    if (k > PP) k = PP;
    if (k <= 0) {
        if (tid == 0) hard_partial[b] = 0.0f;
        return;
    }
    if (tid == 0) { s_prefix = 0u; s_kk = k; }
    __syncthreads();

    unsigned int prefmask = 0u;
    for (int round = 0; round < 4; ++round) {
        const int shift = 24 - 8 * round;
        hist[tid] = 0;
        __syncthreads();
        unsigned int pref = s_prefix;
        for (int i = tid; i < PP; i += 256) {
            unsigned int v = vals[i];
            if ((v & prefmask) == pref)
                atomicAdd(&hist[(v >> shift) & 0xFF], 1);
        }
        __syncthreads();
        scan[tid] = hist[tid];
        __syncthreads();
        for (int off = 1; off < 256; off <<= 1) {
            int add = (tid + off < 256) ? scan[tid + off] : 0;
            __syncthreads();
            scan[tid] += add;
            __syncthreads();
        }
        int sg = scan[tid] - hist[tid];
        int kk = s_kk;
        __syncthreads();
        if (sg < kk && sg + hist[tid] >= kk) {
            s_prefix = pref | ((unsigned int)tid << shift);
            s_kk     = kk - sg;
        }
        __syncthreads();
        prefmask |= (0xFFu << shift);
    }

    unsigned int t = s_prefix;
    int kk = s_kk;
    float tf = __uint_as_float(t);

    float acc = 0.0f;
    for (int i = tid; i < PP; i += 256) {
        unsigned int v = vals[i];
        if (v > t) acc += __uint_as_float(v);
    }
    for (int off = 32; off; off >>= 1) acc += __shfl_xor(acc, off);
    if ((tid & 63) == 0) wsum[tid >> 6] = acc;
    __syncthreads();
    if (tid == 0)
        hard_partial[b] = wsum[0] + wsum[1] + wsum[2] + wsum[3] + (float)kk * tf;
}

// ---------------------------------------------------------------------------
// Kernel 4: combine
// ---------------------------------------------------------------------------
__global__ __launch_bounds__(256) void k4_final(
    const float* __restrict__ clspos_partial,
    const float* __restrict__ bbox_partial,
    const float* __restrict__ hard_partial,
    const int*   __restrict__ pos_count,
    float* __restrict__ out)
{
    const int tid = threadIdx.x;
    float cacc = 0.0f, bacc = 0.0f, hacc = 0.0f;
    int   pacc = 0;
    for (int i = tid; i < K2_BLOCKS; i += 256) cacc += clspos_partial[i];
    if (tid < BB) {
        bacc = bbox_partial[tid];
        hacc = hard_partial[tid];
        pacc = pos_count[tid];
    }
    __shared__ float sc[256], sb[256], sh[256];
    __shared__ int   sp[256];
    sc[tid] = cacc; sb[tid] = bacc; sh[tid] = hacc; sp[tid] = pacc;
    __syncthreads();
    for (int off = 128; off; off >>= 1) {
        if (tid < off) {
            sc[tid] += sc[tid + off];
            sb[tid] += sb[tid + off];
            sh[tid] += sh[tid + off];
            sp[tid] += sp[tid + off];
        }
        __syncthreads();
    }
    if (tid == 0) {
        float npos = fmaxf((float)sp[0], 1.0f);
        out[0] = (sc[0] + sh[0]) / npos + sb[0] / (npos * 4.0f);
    }
}

// ---------------------------------------------------------------------------
extern "C" void kernel_launch(void* const* d_in, const int* in_sizes, int n_in,
                              void* d_out, int out_size, void* d_ws, size_t ws_size,
                              hipStream_t stream) {
    const float* pred_boxes  = (const float*)d_in[0];
    const float* pred_scores = (const float*)d_in[1];
    const float* tgt_boxes   = (const float*)d_in[2];
    const int*   tgt_labels  = (const int*)d_in[3];
    const float* dboxes      = (const float*)d_in[4];
    float* out = (float*)d_out;

    char* ws = (char*)d_ws;
    int*   tlab           = (int*)ws;   ws += (size_t)BB * PP * sizeof(int);
    float* neg            = (float*)ws; ws += (size_t)BB * PP * sizeof(float);
    int*   pos_count      = (int*)ws;   ws += BB * sizeof(int);
    float* bbox_partial   = (float*)ws; ws += BB * sizeof(float);
    float* hard_partial   = (float*)ws; ws += BB * sizeof(float);
    float* clspos_partial = (float*)ws; ws += K2_BLOCKS * sizeof(float);

    k1_match<<<BB, K1_THREADS, 0, stream>>>(pred_boxes, tgt_boxes, tgt_labels, dboxes,
                                            tlab, bbox_partial, pos_count);
    k2_cls<<<K2_BLOCKS, 256, 0, stream>>>(pred_scores, tlab, neg, clspos_partial);
    k3_topk<<<BB, 256, 0, stream>>>(neg, pos_count, hard_partial);
    k4_final<<<1, 256, 0, stream>>>(clspos_partial, bbox_partial, hard_partial,
                                    pos_count, out);
}